// Round 1
// baseline (1402.837 us; speedup 1.0000x reference)
//
#include <hip/hip_runtime.h>
#include <cstdint>

// VisionMambaLite forward on gfx950.
// R8: in-proj and dt-proj GEMMs moved to a 256x256 8-phase schedule
// (K-half panels, counted vmcnt(6), raw s_barrier, setprio around MFMA,
// bijective XCD swizzle). out-proj / patch-embed stay on the 128^2 kernel
// (N=512 -> only 98 blocks at 256^2; tail quantization would lose).
// R7 = R6 with the k_cvt1 grid typo fixed.

using u16 = unsigned short;
typedef __attribute__((ext_vector_type(8))) short   bfrag;
typedef __attribute__((ext_vector_type(4))) float   ffrag;
typedef __attribute__((ext_vector_type(8))) u16     u16x8;

__device__ __forceinline__ float b2f(u16 u) {
  union { float f; uint32_t i; } c; c.i = ((uint32_t)u) << 16; return c.f;
}
__device__ __forceinline__ u16 f2b(float f) {
  union { float f; uint32_t i; } c; c.f = f;
  uint32_t r = c.i + 0x7FFFu + ((c.i >> 16) & 1u);
  return (u16)(r >> 16);
}

#define LOG2E 1.44269504f
#define LN2   0.69314718f
__device__ __forceinline__ float fexp(float x) {
  return __builtin_amdgcn_exp2f(x * LOG2E);
}
__device__ __forceinline__ float fsigmoid(float x) {
  return __builtin_amdgcn_rcpf(1.f + __builtin_amdgcn_exp2f(-x * LOG2E));
}
__device__ __forceinline__ float fsilu(float x) { return x * fsigmoid(x); }
__device__ __forceinline__ float fsoftplus(float x) {
  float e = __builtin_amdgcn_exp2f(-fabsf(x) * LOG2E);
  return fmaxf(x, 0.f) + LN2 * __builtin_amdgcn_logf(1.f + e);
}

__device__ __forceinline__ void gl_lds16(const u16* g, u16* l) {
  __builtin_amdgcn_global_load_lds(
      (const __attribute__((address_space(1))) void*)g,
      (__attribute__((address_space(3))) void*)l,
      16, 0, 0);
}

// ---------------------------------------------------------------------------
// 256x256 8-phase dual GEMM (bf16, K multiple of 64, M multiple of 256,
// N per path multiple of 256).  C[m,col] = sum_k A[m,acol+k]*W[n,k].
//
// Panel stream per K-tile T: {Ak0,Bk0,Ak1,Bk1} (256x32 bf16 = 16 KiB each),
// panel n lives in LDS slot n&7.  Phase P=4T+q issues the stage of panel
// P+7; each panel's LDS reads all happen in ONE phase (Ak0,Bk0 @ph0,
// Ak1 @ph1, Bk1 @ph2), so the slot being overwritten was last read >=1
// barrier-separated phase before the stage issue (WAR-safe).  vmcnt(6)
// (= 3 panels x 2 loads/wave) at each tile boundary; vmcnt(0) only when
// entering the final tile.
//
// LDS panel layout: 128 rows x 128 B; LDS-row j holds M-rows {2j,2j+1};
// 16B chunk c' = (((r&1)<<2)|fq) ^ (j&7)  (XOR swizzle, conflict-free for
// the 16-row x 8-elem ds_read_b128 fragment pattern; staging inverts the
// map on the GLOBAL address so global_load_lds stays linear).
// ---------------------------------------------------------------------------
__global__ __launch_bounds__(512, 2)
void gemm_256(const u16* __restrict__ A, const u16* __restrict__ W1,
              const u16* __restrict__ W2, u16* __restrict__ C,
              int K, int lda, int ldc, int nsplit, int acol2, int ccol2)
{
  __shared__ u16 lds[65536];          // 8 slots x 8192 u16 (16 KiB)

  // bijective XCD swizzle (works for grid not divisible by 8)
  const int nwg  = gridDim.x * gridDim.y;
  const int flat = blockIdx.y * gridDim.x + blockIdx.x;
  const int q8 = nwg >> 3, r8 = nwg & 7;
  const int xcd = flat & 7, sidx = flat >> 3;
  const int f2 = (xcd < r8 ? xcd * (q8 + 1)
                           : r8 * (q8 + 1) + (xcd - r8) * q8) + sidx;
  const int bx = f2 % gridDim.x;
  const int by = f2 / gridDim.x;

  const bool second = bx >= nsplit;
  const u16* W    = second ? W2 : W1;
  const int n0l   = (bx - (second ? nsplit : 0)) * 256;
  const int acol  = second ? acol2 : 0;
  const int ccol0 = n0l + (second ? ccol2 : 0);
  const int m0    = by * 256;

  const int tid  = threadIdx.x;
  const int lane = tid & 63;
  const int w    = tid >> 6;          // wave 0..7
  const int wm   = w >> 2;            // 0..1  (row half of C tile)
  const int wn   = w & 3;             // 0..3  (col quarter of C tile)

  // ---- staging map: thread covers LDS bytes (2w+l)*1024 + lane*16 ----
  const int jj0 = (w * 2 + 0) * 8 + (lane >> 3);
  const int jj1 = (w * 2 + 1) * 8 + (lane >> 3);
  const int cc  = lane & 7;
  const int ch0 = cc ^ (jj0 & 7);
  const int ch1 = cc ^ (jj1 & 7);
  const int r0 = 2 * jj0 + (ch0 >> 2), fq0 = ch0 & 3;
  const int r1 = 2 * jj1 + (ch1 >> 2), fq1 = ch1 & 3;
  const uint32_t aoff0 = (uint32_t)(m0 + r0) * lda + acol + fq0 * 8;
  const uint32_t aoff1 = (uint32_t)(m0 + r1) * lda + acol + fq1 * 8;
  const uint32_t boff0 = (uint32_t)(n0l + r0) * K + fq0 * 8;
  const uint32_t boff1 = (uint32_t)(n0l + r1) * K + fq1 * 8;
  u16* ldss0 = &lds[(w * 2 + 0) * 512];
  u16* ldss1 = &lds[(w * 2 + 1) * 512];

  auto STAGE_A = [&](int kk, int slot) {
    gl_lds16(A + aoff0 + kk, ldss0 + slot * 8192);
    gl_lds16(A + aoff1 + kk, ldss1 + slot * 8192);
  };
  auto STAGE_B = [&](int kk, int slot) {
    gl_lds16(W + boff0 + kk, ldss0 + slot * 8192);
    gl_lds16(W + boff1 + kk, ldss1 + slot * 8192);
  };

  // ---- fragment-read offsets (bytes within a panel) ----
  const int fr  = lane & 15;
  const int fqc = lane >> 4;
  const int j0a = wm * 64 + (fr >> 1);
  const int j0b = wn * 32 + (fr >> 1);
  const int offA = j0a * 128 + (((((fr & 1) << 2) | fqc) ^ (j0a & 7)) << 4);
  const int offB = j0b * 128 + (((((fr & 1) << 2) | fqc) ^ (j0b & 7)) << 4);
  const char* ldsc = (const char*)lds;

  const ffrag fz = {0.f, 0.f, 0.f, 0.f};
  ffrag acc[8][4];
#pragma unroll
  for (int i = 0; i < 8; ++i)
#pragma unroll
    for (int j = 0; j < 4; ++j) acc[i][j] = fz;

  const int NT = K >> 6;

  // prologue: panels 0..6 (tile0 complete + tile1 {Ak0,Bk0,Ak1})
  STAGE_A(0, 0);  STAGE_B(0, 1);  STAGE_A(32, 2);  STAGE_B(32, 3);
  STAGE_A(64, 4); STAGE_B(64, 5); STAGE_A(96, 6);
  asm volatile("s_waitcnt vmcnt(6)" ::: "memory");
  __builtin_amdgcn_s_barrier();

  bfrag a0[8], a1[8], b0[4], b1[4];
  for (int T = 0; T < NT; ++T) {
    const int sb = (T & 1) << 2;
    const int so = sb ^ 4;
    const char* pA0 = ldsc + (sb + 0) * 16384;
    const char* pB0 = ldsc + (sb + 1) * 16384;
    const char* pA1 = ldsc + (sb + 2) * 16384;
    const char* pB1 = ldsc + (sb + 3) * 16384;

    // ---- ph0: read Ak0 (8) + Bk0 (4); stage Bk1(T+1); MFMA k0,rows0-63 ----
#pragma unroll
    for (int t = 0; t < 8; ++t)
      a0[t] = *(const bfrag*)(pA0 + offA + t * 1024);
#pragma unroll
    for (int c = 0; c < 4; ++c)
      b0[c] = *(const bfrag*)(pB0 + offB + c * 1024);
    if (T + 1 < NT) STAGE_B((T + 1) * 64 + 32, so + 3);
    __builtin_amdgcn_s_barrier();
    __builtin_amdgcn_s_setprio(1);
#pragma unroll
    for (int i = 0; i < 4; ++i)
#pragma unroll
      for (int j = 0; j < 4; ++j)
        acc[i][j] = __builtin_amdgcn_mfma_f32_16x16x32_bf16(
            a0[i], b0[j], acc[i][j], 0, 0, 0);
    __builtin_amdgcn_s_setprio(0);
    __builtin_amdgcn_s_barrier();

    // ---- ph1: read Ak1 (8); stage Ak0(T+2); MFMA k0, rows 64-127 ----
#pragma unroll
    for (int t = 0; t < 8; ++t)
      a1[t] = *(const bfrag*)(pA1 + offA + t * 1024);
    if (T + 2 < NT) STAGE_A((T + 2) * 64, sb + 0);
    __builtin_amdgcn_s_barrier();
    __builtin_amdgcn_s_setprio(1);
#pragma unroll
    for (int i = 0; i < 4; ++i)
#pragma unroll
      for (int j = 0; j < 4; ++j)
        acc[4 + i][j] = __builtin_amdgcn_mfma_f32_16x16x32_bf16(
            a0[4 + i], b0[j], acc[4 + i][j], 0, 0, 0);
    __builtin_amdgcn_s_setprio(0);
    __builtin_amdgcn_s_barrier();

    // ---- ph2: read Bk1 (4); stage Bk0(T+2); MFMA k1, rows 0-63 ----
#pragma unroll
    for (int c = 0; c < 4; ++c)
      b1[c] = *(const bfrag*)(pB1 + offB + c * 1024);
    if (T + 2 < NT) STAGE_B((T + 2) * 64, sb + 1);
    __builtin_amdgcn_s_barrier();
    __builtin_amdgcn_s_setprio(1);
#pragma unroll
    for (int i = 0; i < 4; ++i)
#pragma unroll
      for (int j = 0; j < 4; ++j)
        acc[i][j] = __builtin_amdgcn_mfma_f32_16x16x32_bf16(
            a1[i], b1[j], acc[i][j], 0, 0, 0);
    __builtin_amdgcn_s_setprio(0);
    __builtin_amdgcn_s_barrier();

    // ---- ph3: stage Ak1(T+2); MFMA k1, rows 64-127; boundary vmcnt ----
    if (T + 2 < NT) STAGE_A((T + 2) * 64 + 32, sb + 2);
    __builtin_amdgcn_s_barrier();
    __builtin_amdgcn_s_setprio(1);
#pragma unroll
    for (int i = 0; i < 4; ++i)
#pragma unroll
      for (int j = 0; j < 4; ++j)
        acc[4 + i][j] = __builtin_amdgcn_mfma_f32_16x16x32_bf16(
            a1[4 + i], b1[j], acc[4 + i][j], 0, 0, 0);
    __builtin_amdgcn_s_setprio(0);
    if (T + 2 < NT)
      asm volatile("s_waitcnt vmcnt(6)" ::: "memory");
    else if (T + 2 == NT)
      asm volatile("s_waitcnt vmcnt(0)" ::: "memory");
    __builtin_amdgcn_s_barrier();
  }

#pragma unroll
  for (int i = 0; i < 8; ++i)
#pragma unroll
    for (int j = 0; j < 4; ++j)
#pragma unroll
      for (int rg = 0; rg < 4; ++rg) {
        int row = m0 + wm * 128 + i * 16 + fqc * 4 + rg;
        int col = ccol0 + wn * 64 + j * 16 + fr;
        C[(size_t)row * ldc + col] = f2b(acc[i][j][rg]);
      }
}

// ---------------------------------------------------------------------------
// Dual GEMM 128^2 (kept for N=512 shapes: patch embed, out-proj).
// grid total must be divisible by 8.
// ---------------------------------------------------------------------------
__global__ __launch_bounds__(256, 2)
void gemm_dual(const u16* __restrict__ A, const u16* __restrict__ W1,
               const u16* __restrict__ W2, u16* __restrict__ C,
               int K, int lda, int ldc, int nsplit, int acol2, int ccol2)
{
  __shared__ u16 As[128 * 64];
  __shared__ u16 Bs[128 * 64];

  // XCD swizzle
  const int total = gridDim.x * gridDim.y;
  const int flat  = blockIdx.y * gridDim.x + blockIdx.x;
  const int chunk = total >> 3;
  const int f2    = (flat & 7) * chunk + (flat >> 3);
  const int bx    = f2 % gridDim.x;
  const int by    = f2 / gridDim.x;

  const bool second = bx >= nsplit;
  const u16* W     = second ? W2 : W1;
  const int n0l    = (bx - (second ? nsplit : 0)) * 128;
  const int acol   = second ? acol2 : 0;
  const int ccol0  = n0l + (second ? ccol2 : 0);
  const int m0     = by * 128;

  const int tid  = threadIdx.x;
  const int lane = tid & 63;
  const int wv   = tid >> 6;
  const int wm   = wv >> 1;
  const int wn   = wv & 1;

  const int lr   = lane >> 3;
  const int lc   = lane & 7;
  const int kcol = (lc ^ lr) << 3;

  const size_t abase = (size_t)(m0 + wv * 32 + lr) * lda + acol + kcol;
  const size_t wbase = (size_t)(n0l + wv * 32 + lr) * K + kcol;

  const ffrag fz = {0.f, 0.f, 0.f, 0.f};
  ffrag acc[4][4];
#pragma unroll
  for (int i = 0; i < 4; ++i)
#pragma unroll
    for (int j = 0; j < 4; ++j) acc[i][j] = fz;

  const int fr = lane & 15;
  const int fq = lane >> 4;

  for (int kb = 0; kb < K; kb += 64) {
#pragma unroll
    for (int i = 0; i < 4; ++i)
      gl_lds16(A + abase + (size_t)(i * 8) * lda + kb, &As[(wv * 4 + i) * 512]);
#pragma unroll
    for (int i = 0; i < 4; ++i)
      gl_lds16(W + wbase + (size_t)(i * 8) * K + kb, &Bs[(wv * 4 + i) * 512]);
    __syncthreads();

#pragma unroll
    for (int ks = 0; ks < 2; ++ks) {
      bfrag af[4], bfr[4];
#pragma unroll
      for (int t = 0; t < 4; ++t) {
        int r  = wm * 64 + t * 16 + fr;
        int ca = ((ks * 4 + fq) ^ (r & 7)) << 3;
        af[t]  = *(const bfrag*)&As[r * 64 + ca];
        int n  = wn * 64 + t * 16 + fr;
        int cb = ((ks * 4 + fq) ^ (n & 7)) << 3;
        bfr[t] = *(const bfrag*)&Bs[n * 64 + cb];
      }
#pragma unroll
      for (int i = 0; i < 4; ++i)
#pragma unroll
        for (int j = 0; j < 4; ++j)
          acc[i][j] = __builtin_amdgcn_mfma_f32_16x16x32_bf16(
              af[i], bfr[j], acc[i][j], 0, 0, 0);
    }
    __syncthreads();
  }

#pragma unroll
  for (int i = 0; i < 4; ++i)
#pragma unroll
    for (int j = 0; j < 4; ++j)
#pragma unroll
      for (int rg = 0; rg < 4; ++rg) {
        int row = m0 + wm * 64 + i * 16 + fq * 4 + rg;
        int col = ccol0 + wn * 64 + j * 16 + fr;
        C[(size_t)row * ldc + col] = f2b(acc[i][j][rg]);
      }
}

// ---------------------------------------------------------------------------
// W' precompute GEMM: z = L*2+path. C[c,d] = sum_{c'} fus[c, path*512+c'] *
// OT[z][d, c']  ->  WF[L][c*1536 + path*768 + d].  M=512, N=768, K=512.
// ---------------------------------------------------------------------------
__global__ __launch_bounds__(256, 2)
void gemm_wprep(const u16* __restrict__ WB, const u16* __restrict__ OT,
                u16* __restrict__ WF)
{
  __shared__ u16 As[128 * 64];
  __shared__ u16 Bs[128 * 64];

  const int z = blockIdx.z, L = z >> 1, path = z & 1;
  const u16* A = WB + (size_t)L * 4063232 + 3538944;   // fus bf16, lda 1024
  const u16* W = OT + (size_t)z * 393216;              // 768 x 512
  u16* C = WF + (size_t)L * 786432;

  const int m0 = blockIdx.y * 128, n0l = blockIdx.x * 128;
  const int acol = path * 512, ccol = path * 768;

  const int tid  = threadIdx.x;
  const int lane = tid & 63;
  const int wv   = tid >> 6;
  const int wm   = wv >> 1;
  const int wn   = wv & 1;
  const int lr   = lane >> 3;
  const int lc   = lane & 7;
  const int kcol = (lc ^ lr) << 3;

  const size_t abase = (size_t)(m0 + wv * 32 + lr) * 1024 + acol + kcol;
  const size_t wbase = (size_t)(n0l + wv * 32 + lr) * 512 + kcol;

  const ffrag fz = {0.f, 0.f, 0.f, 0.f};
  ffrag acc[4][4];
#pragma unroll
  for (int i = 0; i < 4; ++i)
#pragma unroll
    for (int j = 0; j < 4; ++j) acc[i][j] = fz;

  const int fr = lane & 15;
  const int fq = lane >> 4;

  for (int kb = 0; kb < 512; kb += 64) {
#pragma unroll
    for (int i = 0; i < 4; ++i)
      gl_lds16(A + abase + (size_t)(i * 8) * 1024 + kb, &As[(wv * 4 + i) * 512]);
#pragma unroll
    for (int i = 0; i < 4; ++i)
      gl_lds16(W + wbase + (size_t)(i * 8) * 512 + kb, &Bs[(wv * 4 + i) * 512]);
    __syncthreads();

#pragma unroll
    for (int ks = 0; ks < 2; ++ks) {
      bfrag af[4], bfr[4];
#pragma unroll
      for (int t = 0; t < 4; ++t) {
        int r  = wm * 64 + t * 16 + fr;
        int ca = ((ks * 4 + fq) ^ (r & 7)) << 3;
        af[t]  = *(const bfrag*)&As[r * 64 + ca];
        int n  = wn * 64 + t * 16 + fr;
        int cb = ((ks * 4 + fq) ^ (n & 7)) << 3;
        bfr[t] = *(const bfrag*)&Bs[n * 64 + cb];
      }
#pragma unroll
      for (int i = 0; i < 4; ++i)
#pragma unroll
        for (int j = 0; j < 4; ++j)
          acc[i][j] = __builtin_amdgcn_mfma_f32_16x16x32_bf16(
              af[i], bfr[j], acc[i][j], 0, 0, 0);
    }
    __syncthreads();
  }

#pragma unroll
  for (int i = 0; i < 4; ++i)
#pragma unroll
    for (int j = 0; j < 4; ++j)
#pragma unroll
      for (int rg = 0; rg < 4; ++rg) {
        int row = m0 + wm * 64 + i * 16 + fq * 4 + rg;
        int col = ccol + n0l + wn * 64 + j * 16 + fr;
        C[(size_t)row * 1536 + col] = f2b(acc[i][j][rg]);
      }
}

// transpose out_w: OT[z][d][c'] = out_path[L][c'][d], f32 -> bf16.
__global__ __launch_bounds__(256)
void k_transp(const float* __restrict__ mho, const float* __restrict__ mvo,
              u16* __restrict__ OT)
{
  __shared__ float ld[32][33];
  const int z = blockIdx.z, L = z >> 1, path = z & 1;
  const float* src = (path ? mvo : mho) + (size_t)L * 393216;
  u16* dst = OT + (size_t)z * 393216;
  const int tx = threadIdx.x & 31, ty = threadIdx.x >> 5;
  const int dx = blockIdx.x * 32, cy = blockIdx.y * 32;
#pragma unroll
  for (int i = 0; i < 4; ++i)
    ld[ty + 8 * i][tx] = src[(size_t)(cy + ty + 8 * i) * 768 + dx + tx];
  __syncthreads();
#pragma unroll
  for (int i = 0; i < 4; ++i)
    dst[(size_t)(dx + ty + 8 * i) * 512 + cy + tx] = f2b(ld[tx][ty + 8 * i]);
}

// ---------------------------------------------------------------------------
// weight conversion f32 -> bf16, all 6 layers x 7 regions in one dispatch.
// ---------------------------------------------------------------------------
__global__ __launch_bounds__(256)
void k_cvt_all(const float* __restrict__ mhi, const float* __restrict__ mhd,
               const float* __restrict__ mho, const float* __restrict__ mvi,
               const float* __restrict__ mvd, const float* __restrict__ mvo,
               const float* __restrict__ fus, u16* __restrict__ dst)
{
  size_t e = ((size_t)blockIdx.x * 256 + threadIdx.x) * 8;  // < 24,379,392
  int L = (int)(e / 4063232);
  int r = (int)(e - (size_t)L * 4063232);
  const float* s; int off;
  if      (r <  786432) { s = mhi + (size_t)L *  786432; off = r; }
  else if (r < 1376256) { s = mhd + (size_t)L *  589824; off = r -  786432; }
  else if (r < 1769472) { s = mho + (size_t)L *  393216; off = r - 1376256; }
  else if (r < 2555904) { s = mvi + (size_t)L *  786432; off = r - 1769472; }
  else if (r < 3145728) { s = mvd + (size_t)L *  589824; off = r - 2555904; }
  else if (r < 3538944) { s = mvo + (size_t)L *  393216; off = r - 3145728; }
  else                  { s = fus + (size_t)L *  524288; off = r - 3538944; }
  float4 a = *(const float4*)(s + off);
  float4 b = *(const float4*)(s + off + 4);
  u16x8 o;
  o[0] = f2b(a.x); o[1] = f2b(a.y); o[2] = f2b(a.z); o[3] = f2b(a.w);
  o[4] = f2b(b.x); o[5] = f2b(b.y); o[6] = f2b(b.z); o[7] = f2b(b.w);
  *(u16x8*)(dst + e) = o;
}

__global__ __launch_bounds__(256)
void k_cvt1(const float* __restrict__ s, u16* __restrict__ dst)
{
  int e = (blockIdx.x * 256 + threadIdx.x) * 8;
  float4 a = *(const float4*)(s + e);
  float4 b = *(const float4*)(s + e + 4);
  u16x8 o;
  o[0] = f2b(a.x); o[1] = f2b(a.y); o[2] = f2b(a.z); o[3] = f2b(a.w);
  o[4] = f2b(b.x); o[5] = f2b(b.y); o[6] = f2b(b.z); o[7] = f2b(b.w);
  *(u16x8*)(dst + e) = o;
}

__global__ __launch_bounds__(256) void k_im2col(const float* __restrict__ x,
                                                u16* __restrict__ im)
{
  int idx = blockIdx.x * 256 + threadIdx.x;     // 12544*96
  int r = idx % 96, p = idx / 96;
  int b = p / 196, q = p - b * 196;
  int ph = q / 14, pw = q - ph * 14;
  int k = r * 8;
  int c = k >> 8, k2 = k & 255;
  int i = k2 >> 4, j = k2 & 15;
  const float* src = x + (((size_t)(b * 3 + c) * 224 + ph * 16 + i) * 224
                          + pw * 16 + j);
  float4 a = *(const float4*)src;
  float4 d = *(const float4*)(src + 4);
  u16x8 o;
  o[0] = f2b(a.x); o[1] = f2b(a.y); o[2] = f2b(a.z); o[3] = f2b(a.w);
  o[4] = f2b(d.x); o[5] = f2b(d.y); o[6] = f2b(d.z); o[7] = f2b(d.w);
  *(u16x8*)(im + (size_t)p * 768 + k) = o;
}

// TOK = LN_blk0(TOK + patch_b + pos), in place (fused addbias + first LN)
__global__ __launch_bounds__(256)
void k_addbias_ln(u16* __restrict__ TOK, const float* __restrict__ pb,
                  const float* __restrict__ pos, const float* __restrict__ w,
                  const float* __restrict__ b)
{
  int row  = blockIdx.x * 4 + (threadIdx.x >> 6);
  int lane = threadIdx.x & 63;
  int base = lane * 8;
  int tpos = 1 + (row % 196);
  u16* p = TOK + (size_t)row * 512 + base;
  u16x8 t = *(u16x8*)p;
  const float* pv = pos + (size_t)tpos * 512 + base;
  float v[8]; float s = 0.f, qq = 0.f;
#pragma unroll
  for (int i = 0; i < 8; ++i) {
    v[i] = b2f(t[i]) + pb[base + i] + pv[i];
    s += v[i]; qq += v[i] * v[i];
  }
#pragma unroll
  for (int o = 32; o; o >>= 1) { s += __shfl_xor(s, o, 64); qq += __shfl_xor(qq, o, 64); }
  float mean = s * (1.f / 512.f);
  float rstd = rsqrtf(qq * (1.f / 512.f) - mean * mean + 1e-5f);
  u16x8 ov;
#pragma unroll
  for (int i = 0; i < 8; ++i)
    ov[i] = f2b((v[i] - mean) * rstd * w[base + i] + b[base + i]);
  *(u16x8*)p = ov;
}

// TOK = LN_ss(YF + fus_b + TOK)  [plain, used for last layer]
__global__ __launch_bounds__(256) void k_ln_fuse(const u16* __restrict__ YF,
                                                 u16* __restrict__ TOK,
                                                 const float* __restrict__ fb,
                                                 const float* __restrict__ w,
                                                 const float* __restrict__ b)
{
  int row  = blockIdx.x * 4 + (threadIdx.x >> 6);
  int lane = threadIdx.x & 63;
  int base = lane * 8;
  const u16* yf = YF + (size_t)row * 512 + base;
  u16* tp = TOK + (size_t)row * 512 + base;
  u16x8 yv = *(const u16x8*)yf;
  u16x8 tv = *(u16x8*)tp;
  float v[8]; float s = 0.f, qq = 0.f;
#pragma unroll
  for (int i = 0; i < 8; ++i) {
    v[i] = b2f(yv[i]) + fb[base + i] + b2f(tv[i]);
    s += v[i]; qq += v[i] * v[i];
  }
#pragma unroll
  for (int o = 32; o; o >>= 1) { s += __shfl_xor(s, o, 64); qq += __shfl_xor(qq, o, 64); }
  float mean = s * (1.f / 512.f);
  float rstd = rsqrtf(qq * (1.f / 512.f) - mean * mean + 1e-5f);
  u16x8 ov;
#pragma unroll
  for (int i = 0; i < 8; ++i)
    ov[i] = f2b((v[i] - mean) * rstd * w[base + i] + b[base + i]);
  *(u16x8*)tp = ov;
}

// TOK = LN_blk(LN_ss(YF + fus_b + TOK))  (fused; t stays in f32 regs)
__global__ __launch_bounds__(256)
void k_ln_fuse2(const u16* __restrict__ YF, u16* __restrict__ TOK,
                const float* __restrict__ fb, const float* __restrict__ w1,
                const float* __restrict__ b1, const float* __restrict__ w2,
                const float* __restrict__ b2)
{
  int row  = blockIdx.x * 4 + (threadIdx.x >> 6);
  int lane = threadIdx.x & 63;
  int base = lane * 8;
  const u16* yf = YF + (size_t)row * 512 + base;
  u16* tp = TOK + (size_t)row * 512 + base;
  u16x8 yv = *(const u16x8*)yf;
  u16x8 tv = *(u16x8*)tp;
  float v[8]; float s = 0.f, qq = 0.f;
#pragma unroll
  for (int i = 0; i < 8; ++i) {
    v[i] = b2f(yv[i]) + fb[base + i] + b2f(tv[i]);
    s += v[i]; qq += v[i] * v[i];
  }
#pragma unroll
  for (int o = 32; o; o >>= 1) { s += __shfl_xor(s, o, 64); qq += __shfl_xor(qq, o, 64); }
  float mean = s * (1.f / 512.f);
  float rstd = rsqrtf(qq * (1.f / 512.f) - mean * mean + 1e-5f);
  float s2 = 0.f, q2 = 0.f;
#pragma unroll
  for (int i = 0; i < 8; ++i) {
    v[i] = (v[i] - mean) * rstd * w1[base + i] + b1[base + i];
    s2 += v[i]; q2 += v[i] * v[i];
  }
#pragma unroll
  for (int o = 32; o; o >>= 1) { s2 += __shfl_xor(s2, o, 64); q2 += __shfl_xor(q2, o, 64); }
  float m2 = s2 * (1.f / 512.f);
  float r2 = rsqrtf(q2 * (1.f / 512.f) - m2 * m2 + 1e-5f);
  u16x8 ov;
#pragma unroll
  for (int i = 0; i < 8; ++i)
    ov[i] = f2b((v[i] - m2) * r2 * w2[base + i] + b2[base + i]);
  *(u16x8*)tp = ov;
}

// conv3+silu, h+v, 2 d's per thread (u32 bf16x2)
__global__ __launch_bounds__(256)
void k_conv_hv(const u16* __restrict__ XZ,
               const float* __restrict__ cwh, const float* __restrict__ cbh,
               const float* __restrict__ cwv, const float* __restrict__ cbv,
               u16* __restrict__ XC)
{
  int idx = blockIdx.x * 256 + threadIdx.x;   // 2*896*384
  int half = idx >= 344064;
  int t = idx - (half ? 344064 : 0);
  int dp = t % 384, sq = t / 384;
  int d0 = dp * 2;
  int rowbase, rowstride;
  if (!half) { rowbase = sq * 14; rowstride = 1; }
  else       { int b = sq / 14, wq = sq - b * 14; rowbase = b * 196 + wq; rowstride = 14; }
  const float* cw = half ? cwv : cwh;
  const float* cb = half ? cbv : cbh;
  int xio = half ? 1536 : 0, xco = half ? 768 : 0;
  float w0a = cw[d0 * 3 + 0], w1a = cw[d0 * 3 + 1], w2a = cw[d0 * 3 + 2];
  float w0b = cw[d0 * 3 + 3], w1b = cw[d0 * 3 + 4], w2b = cw[d0 * 3 + 5];
  float ba = cb[d0], bb = cb[d0 + 1];
  uint32_t cu = *(const uint32_t*)&XZ[(size_t)rowbase * 3072 + xio + d0];
  float pa = 0.f, pb = 0.f;
  float ca = b2f((u16)cu), cbv2 = b2f((u16)(cu >> 16));
#pragma unroll
  for (int l = 0; l < 14; ++l) {
    int row = rowbase + l * rowstride;
    float na = 0.f, nb = 0.f;
    if (l < 13) {
      uint32_t nu = *(const uint32_t*)&XZ[(size_t)(row + rowstride) * 3072 + xio + d0];
      na = b2f((u16)nu); nb = b2f((u16)(nu >> 16));
    }
    float ua = pa * w0a + ca * w1a + na * w2a + ba;
    float ub = pb * w0b + cbv2 * w1b + nb * w2b + bb;
    uint32_t ov = (uint32_t)f2b(fsilu(ua)) | ((uint32_t)f2b(fsilu(ub)) << 16);
    *(uint32_t*)&XC[(size_t)row * 1536 + xco + d0] = ov;
    pa = ca; pb = cbv2; ca = na; cbv2 = nb;
  }
}

// selective scan, h+v, 2 d's per thread
__global__ __launch_bounds__(256)
void k_scan_hv(const u16* __restrict__ XZ, u16* __restrict__ XC,
               const float* __restrict__ dtbh, const float* __restrict__ Ah,
               const float* __restrict__ Dh,
               const float* __restrict__ dtbv, const float* __restrict__ Av,
               const float* __restrict__ Dv)
{
  int idx = blockIdx.x * 256 + threadIdx.x;   // 2*896*384
  int half = idx >= 344064;
  int t = idx - (half ? 344064 : 0);
  int dp = t % 384, sq = t / 384;
  int d0 = dp * 2;
  int rowbase, rowstride;
  if (!half) { rowbase = sq * 14; rowstride = 1; }
  else       { int b = sq / 14, wq = sq - b * 14; rowbase = b * 196 + wq; rowstride = 14; }
  int xio = half ? 1536 : 0, xco = half ? 768 : 0;
  const float* dtb = half ? dtbv : dtbh;
  const float* Ap  = half ? Av : Ah;
  const float* Dp  = half ? Dv : Dh;
  float dba = dtb[d0], dbb = dtb[d0 + 1];
  float Aa = Ap[d0], Ab = Ap[d0 + 1];
  float Da = Dp[d0], Db = Dp[d0 + 1];
  float ra = 0.f, rb = 0.f;
#pragma unroll
  for (int l = 0; l < 14; ++l) {
    int row = rowbase + l * rowstride;
    size_t zb = (size_t)row * 3072 + xio;
    size_t cbo = (size_t)row * 1536 + xco;
    uint32_t xcu = *(const uint32_t*)&XC[cbo + d0];
    uint32_t dtu = *(const uint32_t*)&XZ[zb + d0];
    uint32_t zu  = *(const uint32_t*)&XZ[zb + 768 + d0];
    float xca = b2f((u16)xcu), xcb = b2f((u16)(xcu >> 16));
    float dta = fsoftplus(b2f((u16)dtu) + dba);
    float dtbv2 = fsoftplus(b2f((u16)(dtu >> 16)) + dbb);
    float aea = fexp(Aa * dta), aeb = fexp(Ab * dtbv2);
    ra += xca * dta * aea;
    rb += xcb * dtbv2 * aeb;
    float za = b2f((u16)zu), zbv = b2f((u16)(zu >> 16));
    float ya = (ra * aea + xca * Da) * (za * fsigmoid(za));
    float yb = (rb * aeb + xcb * Db) * (zbv * fsigmoid(zbv));
    *(uint32_t*)&XC[cbo + d0] = (uint32_t)f2b(ya) | ((uint32_t)f2b(yb) << 16);
  }
}

// cls token path (batch-invariant, f32)
__global__ void k_cls(const float* __restrict__ cls_tok,
                      const float* __restrict__ pos,
                      const float* __restrict__ bw, const float* __restrict__ bb,
                      float* __restrict__ CLS)
{
  __shared__ float rs[8], rq[8], stat[2];
  int n = threadIdx.x;
  float v = cls_tok[n] + pos[n];
  for (int l = 0; l < 6; ++l) {
    float s = v, q = v * v;
#pragma unroll
    for (int o = 32; o; o >>= 1) { s += __shfl_xor(s, o, 64); q += __shfl_xor(q, o, 64); }
    if ((n & 63) == 0) { rs[n >> 6] = s; rq[n >> 6] = q; }
    __syncthreads();
    if (n == 0) {
      float S = 0.f, Q = 0.f;
      for (int i = 0; i < 8; ++i) { S += rs[i]; Q += rq[i]; }
      float m = S * (1.f / 512.f);
      stat[0] = m; stat[1] = rsqrtf(Q * (1.f / 512.f) - m * m + 1e-5f);
    }
    __syncthreads();
    float u = (v - stat[0]) * stat[1] * bw[l * 512 + n] + bb[l * 512 + n];
    v = v + u;
    __syncthreads();
  }
  CLS[n] = v;
}

// final LN -> f32 out
__global__ __launch_bounds__(256) void k_final(const u16* __restrict__ TOK,
                                               const float* __restrict__ CLS,
                                               const float* __restrict__ w,
                                               const float* __restrict__ b,
                                               float* __restrict__ out)
{
  int row  = blockIdx.x * 4 + (threadIdx.x >> 6);   // < 12608
  int lane = threadIdx.x & 63;
  int bi = row / 197;
  int t  = row - bi * 197;
  int base = lane * 8;
  float v[8]; float s = 0.f, qq = 0.f;
  if (t == 0) {
#pragma unroll
    for (int i = 0; i < 8; ++i) v[i] = CLS[base + i];
  } else {
    const u16* src = TOK + ((size_t)bi * 196 + (t - 1)) * 512 + base;
    u16x8 tv = *(const u16x8*)src;
#pragma unroll
    for (int i = 0; i < 8; ++i) v[i] = b2f(tv[i]);
  }
#pragma unroll
  for (int i = 0; i < 8; ++i) { s += v[i]; qq += v[i] * v[i]; }
#pragma unroll
  for (int o = 32; o; o >>= 1) { s += __shfl_xor(s, o, 64); qq += __shfl_xor(qq, o, 64); }
  float mean = s * (1.f / 512.f);
  float rstd = rsqrtf(qq * (1.f / 512.f) - mean * mean + 1e-5f);
  float* op = out + (size_t)row * 512 + base;
#pragma unroll
  for (int i = 0; i < 8; ++i)
    op[i] = (v[i] - mean) * rstd * w[base + i] + b[base + i];
}

// ---------------------------------------------------------------------------
extern "C" void kernel_launch(void* const* d_in, const int* in_sizes, int n_in,
                              void* d_out, int out_size, void* d_ws, size_t ws_size,
                              hipStream_t stream)
{
  const float* x        = (const float*)d_in[0];
  const float* patch_w  = (const float*)d_in[1];
  const float* patch_b  = (const float*)d_in[2];
  const float* cls_tok  = (const float*)d_in[3];
  const float* pos      = (const float*)d_in[4];
  const float* blk_w    = (const float*)d_in[5];
  const float* blk_b    = (const float*)d_in[6];
  const float* mh_in_w  = (const float*)d_in[7];
  const float* mh_out_w = (const float*)d_in[8];
  const float* mh_cw    = (const float*)d_in[9];
  const float* mh_cb    = (const float*)d_in[10];
  const float* mh_dtw   = (const float*)d_in[11];
  const float* mh_dtb   = (const float*)d_in[12];
  const float* mh_A     = (const float*)d_in[13];
  const float* mh_D     = (const float*)d_in[14];
  const float* mv_in_w  = (const float*)d_in[15];
  const float* mv_out_w = (const float*)d_in[16];
  const float* mv_cw    = (const float*)d_in[17];
  const float* mv_cb    = (const float*)d_in[18];
  const float* mv_dtw   = (const float*)d_in[19];
  const float* mv_dtb   = (const float*)d_in[20];
  const float* mv_A     = (const float*)d_in[21];
  const float* mv_D     = (const float*)d_in[22];
  const float* fus_w    = (const float*)d_in[23];
  const float* fus_b    = (const float*)d_in[24];
  const float* ss_w     = (const float*)d_in[25];
  const float* ss_b     = (const float*)d_in[26];
  const float* fn_w     = (const float*)d_in[27];
  const float* fn_b     = (const float*)d_in[28];

  // workspace layout (bytes), total ~198 MB (ws_size = 256 MiB):
  char* ws = (char*)d_ws;
  u16*   TOK  = (u16*)  (ws);                  // 12544x512  bf16  12,845,056
  u16*   XZHV = (u16*)  (ws +  12845056);      // 12544x3072 bf16  77,070,336
  u16*   XCHV = (u16*)  (ws +  89915392);      // 12544x1536 bf16  38,535,168
  u16*   WB   = (u16*)  (ws + 128450560);      // 6-layer bf16 wts 48,758,784
  u16*   WP   = (u16*)  (ws + 177209344);      // patch_w bf16        786,432
  u16*   OT   = (u16*)  (ws + 178782208);      // out^T bf16        9,437,184
  u16*   WF   = (u16*)  (ws + 188219392);      // W' fused          9,437,184
  float* CLS  = (float*)(ws + 197656576);      // 512 f32
  u16*   IM   = XCHV;                          // im2col aliases XCHV
  u16*   YF   = XZHV;                          // yf GEMM out aliases XZHV

  const size_t LS = 4063232;
  const size_t oMHI = 0, oMHD = 786432, oMVI = 1769472, oMVD = 2555904;

  // one-time: conversions, W' precompute, patch embed, cls
  k_cvt_all<<<11904, 256, 0, stream>>>(mh_in_w, mh_dtw, mh_out_w,
                                       mv_in_w, mv_dtw, mv_out_w, fus_w, WB);
  k_transp<<<dim3(24, 16, 12), 256, 0, stream>>>(mh_out_w, mv_out_w, OT);
  gemm_wprep<<<dim3(6, 4, 12), 256, 0, stream>>>(WB, OT, WF);
  k_cvt1<<<192, 256, 0, stream>>>(patch_w, WP);   // 393,216 elems exactly
  k_im2col<<<4704, 256, 0, stream>>>(x, IM);
  gemm_dual<<<dim3(4, 98), 256, 0, stream>>>(IM, WP, WP, TOK,
                                             768, 768, 512, 4, 0, 0);
  k_addbias_ln<<<3136, 256, 0, stream>>>(TOK, patch_b, pos, blk_w, blk_b);
  k_cls<<<1, 512, 0, stream>>>(cls_tok, pos, blk_w, blk_b, CLS);

  for (int L = 0; L < 6; ++L) {
    const u16* wl = WB + (size_t)L * LS;

    // in-proj (h cols 0..1535, v cols 1536..3071) -- 256^2 8-phase
    gemm_256<<<dim3(12, 49), 512, 0, stream>>>(
        TOK, wl + oMHI, wl + oMVI, XZHV, 512, 512, 3072, 6, 0, 1536);
    // conv3+silu
    k_conv_hv<<<2688, 256, 0, stream>>>(XZHV, mh_cw + L * 2304, mh_cb + L * 768,
                                        mv_cw + L * 2304, mv_cb + L * 768, XCHV);
    // dt-proj (dtraw overwrites xi slots of XZHV) -- 256^2 8-phase
    gemm_256<<<dim3(6, 49), 512, 0, stream>>>(
        XCHV, wl + oMHD, wl + oMVD, XZHV, 768, 1536, 3072, 3, 768, 1536);
    // selective scan (y overwrites xc in XCHV)
    k_scan_hv<<<2688, 256, 0, stream>>>(XZHV, XCHV,
                                        mh_dtb + L * 768, mh_A + L * 768, mh_D + L * 768,
                                        mv_dtb + L * 768, mv_A + L * 768, mv_D + L * 768);
    // fused out-proj + fusion: yf = XCHV @ W'^T  (K=1536, N=512)
    gemm_dual<<<dim3(4, 98), 256, 0, stream>>>(
        XCHV, WF + (size_t)L * 786432, WF + (size_t)L * 786432, YF,
        1536, 1536, 512, 4, 0, 0);
    // residual LN (+ next layer's LN fused, except last layer)
    if (L < 5) {
      k_ln_fuse2<<<3136, 256, 0, stream>>>(YF, TOK, fus_b + L * 512,
                                           ss_w + L * 512, ss_b + L * 512,
                                           blk_w + (L + 1) * 512, blk_b + (L + 1) * 512);
    } else {
      k_ln_fuse<<<3136, 256, 0, stream>>>(YF, TOK, fus_b + L * 512,
                                          ss_w + L * 512, ss_b + L * 512);
    }
  }

  k_final<<<3152, 256, 0, stream>>>(TOK, CLS, fn_w, fn_b, (float*)d_out);
  (void)in_sizes; (void)n_in; (void)out_size; (void)ws_size;
}

// Round 3
// 1256.300 us; speedup vs baseline: 1.1166x; 1.1166x over previous
//
#include <hip/hip_runtime.h>
#include <cstdint>

// VisionMambaLite forward on gfx950.
// R10 = R9 resubmitted (R9 bench was an infra failure: "container failed
// twice", no counters; bounds re-audited, no OOB found).
// R9: revert R8's 256^2 8-phase GEMM (structural loss: 1 block/CU + 588-block
// grid = 2.3 rounds -> 23% round-quantization idle; K=512 too short for the
// deep pipeline). Back to the proven 128^2 gemm_dual (820 TF here).
// New: conv/scan vectorized 2->4 d's per thread (8B/lane loads);
// k_cvt_all trimmed to skip dead mh_out/mv_out regions.

using u16 = unsigned short;
typedef __attribute__((ext_vector_type(8))) short   bfrag;
typedef __attribute__((ext_vector_type(4))) float   ffrag;
typedef __attribute__((ext_vector_type(8))) u16     u16x8;
typedef __attribute__((ext_vector_type(4))) u16     u16x4;

__device__ __forceinline__ float b2f(u16 u) {
  union { float f; uint32_t i; } c; c.i = ((uint32_t)u) << 16; return c.f;
}
__device__ __forceinline__ u16 f2b(float f) {
  union { float f; uint32_t i; } c; c.f = f;
  uint32_t r = c.i + 0x7FFFu + ((c.i >> 16) & 1u);
  return (u16)(r >> 16);
}

#define LOG2E 1.44269504f
#define LN2   0.69314718f
__device__ __forceinline__ float fexp(float x) {
  return __builtin_amdgcn_exp2f(x * LOG2E);
}
__device__ __forceinline__ float fsigmoid(float x) {
  return __builtin_amdgcn_rcpf(1.f + __builtin_amdgcn_exp2f(-x * LOG2E));
}
__device__ __forceinline__ float fsilu(float x) { return x * fsigmoid(x); }
__device__ __forceinline__ float fsoftplus(float x) {
  float e = __builtin_amdgcn_exp2f(-fabsf(x) * LOG2E);
  return fmaxf(x, 0.f) + LN2 * __builtin_amdgcn_logf(1.f + e);
}

__device__ __forceinline__ void gl_lds16(const u16* g, u16* l) {
  __builtin_amdgcn_global_load_lds(
      (const __attribute__((address_space(1))) void*)g,
      (__attribute__((address_space(3))) void*)l,
      16, 0, 0);
}

// ---------------------------------------------------------------------------
// Dual GEMM with XCD swizzle: C[m,col] = sum_k A[m,acol+k]*W[n,k]
// grid total must be divisible by 8. Consecutive blockIdx are assumed
// round-robin across 8 XCDs -> remap so each XCD owns contiguous m-tiles.
// ---------------------------------------------------------------------------
__global__ __launch_bounds__(256, 2)
void gemm_dual(const u16* __restrict__ A, const u16* __restrict__ W1,
               const u16* __restrict__ W2, u16* __restrict__ C,
               int K, int lda, int ldc, int nsplit, int acol2, int ccol2)
{
  __shared__ u16 As[128 * 64];
  __shared__ u16 Bs[128 * 64];

  // XCD swizzle
  const int total = gridDim.x * gridDim.y;
  const int flat  = blockIdx.y * gridDim.x + blockIdx.x;
  const int chunk = total >> 3;
  const int f2    = (flat & 7) * chunk + (flat >> 3);
  const int bx    = f2 % gridDim.x;
  const int by    = f2 / gridDim.x;

  const bool second = bx >= nsplit;
  const u16* W     = second ? W2 : W1;
  const int n0l    = (bx - (second ? nsplit : 0)) * 128;
  const int acol   = second ? acol2 : 0;
  const int ccol0  = n0l + (second ? ccol2 : 0);
  const int m0     = by * 128;

  const int tid  = threadIdx.x;
  const int lane = tid & 63;
  const int wv   = tid >> 6;
  const int wm   = wv >> 1;
  const int wn   = wv & 1;

  const int lr   = lane >> 3;
  const int lc   = lane & 7;
  const int kcol = (lc ^ lr) << 3;

  const size_t abase = (size_t)(m0 + wv * 32 + lr) * lda + acol + kcol;
  const size_t wbase = (size_t)(n0l + wv * 32 + lr) * K + kcol;

  const ffrag fz = {0.f, 0.f, 0.f, 0.f};
  ffrag acc[4][4];
#pragma unroll
  for (int i = 0; i < 4; ++i)
#pragma unroll
    for (int j = 0; j < 4; ++j) acc[i][j] = fz;

  const int fr = lane & 15;
  const int fq = lane >> 4;

  for (int kb = 0; kb < K; kb += 64) {
#pragma unroll
    for (int i = 0; i < 4; ++i)
      gl_lds16(A + abase + (size_t)(i * 8) * lda + kb, &As[(wv * 4 + i) * 512]);
#pragma unroll
    for (int i = 0; i < 4; ++i)
      gl_lds16(W + wbase + (size_t)(i * 8) * K + kb, &Bs[(wv * 4 + i) * 512]);
    __syncthreads();

#pragma unroll
    for (int ks = 0; ks < 2; ++ks) {
      bfrag af[4], bfr[4];
#pragma unroll
      for (int t = 0; t < 4; ++t) {
        int r  = wm * 64 + t * 16 + fr;
        int ca = ((ks * 4 + fq) ^ (r & 7)) << 3;
        af[t]  = *(const bfrag*)&As[r * 64 + ca];
        int n  = wn * 64 + t * 16 + fr;
        int cb = ((ks * 4 + fq) ^ (n & 7)) << 3;
        bfr[t] = *(const bfrag*)&Bs[n * 64 + cb];
      }
#pragma unroll
      for (int i = 0; i < 4; ++i)
#pragma unroll
        for (int j = 0; j < 4; ++j)
          acc[i][j] = __builtin_amdgcn_mfma_f32_16x16x32_bf16(
              af[i], bfr[j], acc[i][j], 0, 0, 0);
    }
    __syncthreads();
  }

#pragma unroll
  for (int i = 0; i < 4; ++i)
#pragma unroll
    for (int j = 0; j < 4; ++j)
#pragma unroll
      for (int rg = 0; rg < 4; ++rg) {
        int row = m0 + wm * 64 + i * 16 + fq * 4 + rg;
        int col = ccol0 + wn * 64 + j * 16 + fr;
        C[(size_t)row * ldc + col] = f2b(acc[i][j][rg]);
      }
}

// ---------------------------------------------------------------------------
// W' precompute GEMM: z = L*2+path. C[c,d] = sum_{c'} fus[c, path*512+c'] *
// OT[z][d, c']  ->  WF[L][c*1536 + path*768 + d].  M=512, N=768, K=512.
// ---------------------------------------------------------------------------
__global__ __launch_bounds__(256, 2)
void gemm_wprep(const u16* __restrict__ WB, const u16* __restrict__ OT,
                u16* __restrict__ WF)
{
  __shared__ u16 As[128 * 64];
  __shared__ u16 Bs[128 * 64];

  const int z = blockIdx.z, L = z >> 1, path = z & 1;
  const u16* A = WB + (size_t)L * 4063232 + 3538944;   // fus bf16, lda 1024
  const u16* W = OT + (size_t)z * 393216;              // 768 x 512
  u16* C = WF + (size_t)L * 786432;

  const int m0 = blockIdx.y * 128, n0l = blockIdx.x * 128;
  const int acol = path * 512, ccol = path * 768;

  const int tid  = threadIdx.x;
  const int lane = tid & 63;
  const int wv   = tid >> 6;
  const int wm   = wv >> 1;
  const int wn   = wv & 1;
  const int lr   = lane >> 3;
  const int lc   = lane & 7;
  const int kcol = (lc ^ lr) << 3;

  const size_t abase = (size_t)(m0 + wv * 32 + lr) * 1024 + acol + kcol;
  const size_t wbase = (size_t)(n0l + wv * 32 + lr) * 512 + kcol;

  const ffrag fz = {0.f, 0.f, 0.f, 0.f};
  ffrag acc[4][4];
#pragma unroll
  for (int i = 0; i < 4; ++i)
#pragma unroll
    for (int j = 0; j < 4; ++j) acc[i][j] = fz;

  const int fr = lane & 15;
  const int fq = lane >> 4;

  for (int kb = 0; kb < 512; kb += 64) {
#pragma unroll
    for (int i = 0; i < 4; ++i)
      gl_lds16(A + abase + (size_t)(i * 8) * 1024 + kb, &As[(wv * 4 + i) * 512]);
#pragma unroll
    for (int i = 0; i < 4; ++i)
      gl_lds16(W + wbase + (size_t)(i * 8) * 512 + kb, &Bs[(wv * 4 + i) * 512]);
    __syncthreads();

#pragma unroll
    for (int ks = 0; ks < 2; ++ks) {
      bfrag af[4], bfr[4];
#pragma unroll
      for (int t = 0; t < 4; ++t) {
        int r  = wm * 64 + t * 16 + fr;
        int ca = ((ks * 4 + fq) ^ (r & 7)) << 3;
        af[t]  = *(const bfrag*)&As[r * 64 + ca];
        int n  = wn * 64 + t * 16 + fr;
        int cb = ((ks * 4 + fq) ^ (n & 7)) << 3;
        bfr[t] = *(const bfrag*)&Bs[n * 64 + cb];
      }
#pragma unroll
      for (int i = 0; i < 4; ++i)
#pragma unroll
        for (int j = 0; j < 4; ++j)
          acc[i][j] = __builtin_amdgcn_mfma_f32_16x16x32_bf16(
              af[i], bfr[j], acc[i][j], 0, 0, 0);
    }
    __syncthreads();
  }

#pragma unroll
  for (int i = 0; i < 4; ++i)
#pragma unroll
    for (int j = 0; j < 4; ++j)
#pragma unroll
      for (int rg = 0; rg < 4; ++rg) {
        int row = m0 + wm * 64 + i * 16 + fq * 4 + rg;
        int col = ccol + n0l + wn * 64 + j * 16 + fr;
        C[(size_t)row * 1536 + col] = f2b(acc[i][j][rg]);
      }
}

// transpose out_w: OT[z][d][c'] = out_path[L][c'][d], f32 -> bf16.
__global__ __launch_bounds__(256)
void k_transp(const float* __restrict__ mho, const float* __restrict__ mvo,
              u16* __restrict__ OT)
{
  __shared__ float ld[32][33];
  const int z = blockIdx.z, L = z >> 1, path = z & 1;
  const float* src = (path ? mvo : mho) + (size_t)L * 393216;
  u16* dst = OT + (size_t)z * 393216;
  const int tx = threadIdx.x & 31, ty = threadIdx.x >> 5;
  const int dx = blockIdx.x * 32, cy = blockIdx.y * 32;
#pragma unroll
  for (int i = 0; i < 4; ++i)
    ld[ty + 8 * i][tx] = src[(size_t)(cy + ty + 8 * i) * 768 + dx + tx];
  __syncthreads();
#pragma unroll
  for (int i = 0; i < 4; ++i)
    dst[(size_t)(dx + ty + 8 * i) * 512 + cy + tx] = f2b(ld[tx][ty + 8 * i]);
}

// ---------------------------------------------------------------------------
// weight conversion f32 -> bf16. Skips mh_out/mv_out regions of WB (never
// read: OT is built from f32 via k_transp). 19,660,800 elems = 9600 blocks.
// WB layout per layer (u16 offsets): mhi@0, mhd@786432, [hole mho],
// mvi@1769472, mvd@2555904, [hole mvo], fus@3538944; stride 4063232.
// ---------------------------------------------------------------------------
__global__ __launch_bounds__(256)
void k_cvt_all(const float* __restrict__ mhi, const float* __restrict__ mhd,
               const float* __restrict__ mvi, const float* __restrict__ mvd,
               const float* __restrict__ fus, u16* __restrict__ dst)
{
  size_t e = ((size_t)blockIdx.x * 256 + threadIdx.x) * 8;  // < 19,660,800
  int L = (int)(e / 3276800);
  int r = (int)(e - (size_t)L * 3276800);
  const float* s; int off; int dsto;
  if      (r <  786432) { s = mhi + (size_t)L * 786432; off = r;           dsto = r; }
  else if (r < 1376256) { s = mhd + (size_t)L * 589824; off = r -  786432; dsto = r; }
  else if (r < 2162688) { s = mvi + (size_t)L * 786432; off = r - 1376256; dsto = r + 393216; }
  else if (r < 2752512) { s = mvd + (size_t)L * 589824; off = r - 2162688; dsto = r + 393216; }
  else                  { s = fus + (size_t)L * 524288; off = r - 2752512; dsto = r + 786432; }
  float4 a = *(const float4*)(s + off);
  float4 b = *(const float4*)(s + off + 4);
  u16x8 o;
  o[0] = f2b(a.x); o[1] = f2b(a.y); o[2] = f2b(a.z); o[3] = f2b(a.w);
  o[4] = f2b(b.x); o[5] = f2b(b.y); o[6] = f2b(b.z); o[7] = f2b(b.w);
  *(u16x8*)(dst + (size_t)L * 4063232 + dsto) = o;
}

__global__ __launch_bounds__(256)
void k_cvt1(const float* __restrict__ s, u16* __restrict__ dst)
{
  int e = (blockIdx.x * 256 + threadIdx.x) * 8;
  float4 a = *(const float4*)(s + e);
  float4 b = *(const float4*)(s + e + 4);
  u16x8 o;
  o[0] = f2b(a.x); o[1] = f2b(a.y); o[2] = f2b(a.z); o[3] = f2b(a.w);
  o[4] = f2b(b.x); o[5] = f2b(b.y); o[6] = f2b(b.z); o[7] = f2b(b.w);
  *(u16x8*)(dst + e) = o;
}

__global__ __launch_bounds__(256) void k_im2col(const float* __restrict__ x,
                                                u16* __restrict__ im)
{
  int idx = blockIdx.x * 256 + threadIdx.x;     // 12544*96
  int r = idx % 96, p = idx / 96;
  int b = p / 196, q = p - b * 196;
  int ph = q / 14, pw = q - ph * 14;
  int k = r * 8;
  int c = k >> 8, k2 = k & 255;
  int i = k2 >> 4, j = k2 & 15;
  const float* src = x + (((size_t)(b * 3 + c) * 224 + ph * 16 + i) * 224
                          + pw * 16 + j);
  float4 a = *(const float4*)src;
  float4 d = *(const float4*)(src + 4);
  u16x8 o;
  o[0] = f2b(a.x); o[1] = f2b(a.y); o[2] = f2b(a.z); o[3] = f2b(a.w);
  o[4] = f2b(d.x); o[5] = f2b(d.y); o[6] = f2b(d.z); o[7] = f2b(d.w);
  *(u16x8*)(im + (size_t)p * 768 + k) = o;
}

// TOK = LN_blk0(TOK + patch_b + pos), in place (fused addbias + first LN)
__global__ __launch_bounds__(256)
void k_addbias_ln(u16* __restrict__ TOK, const float* __restrict__ pb,
                  const float* __restrict__ pos, const float* __restrict__ w,
                  const float* __restrict__ b)
{
  int row  = blockIdx.x * 4 + (threadIdx.x >> 6);
  int lane = threadIdx.x & 63;
  int base = lane * 8;
  int tpos = 1 + (row % 196);
  u16* p = TOK + (size_t)row * 512 + base;
  u16x8 t = *(u16x8*)p;
  const float* pv = pos + (size_t)tpos * 512 + base;
  float v[8]; float s = 0.f, qq = 0.f;
#pragma unroll
  for (int i = 0; i < 8; ++i) {
    v[i] = b2f(t[i]) + pb[base + i] + pv[i];
    s += v[i]; qq += v[i] * v[i];
  }
#pragma unroll
  for (int o = 32; o; o >>= 1) { s += __shfl_xor(s, o, 64); qq += __shfl_xor(qq, o, 64); }
  float mean = s * (1.f / 512.f);
  float rstd = rsqrtf(qq * (1.f / 512.f) - mean * mean + 1e-5f);
  u16x8 ov;
#pragma unroll
  for (int i = 0; i < 8; ++i)
    ov[i] = f2b((v[i] - mean) * rstd * w[base + i] + b[base + i]);
  *(u16x8*)p = ov;
}

// TOK = LN_ss(YF + fus_b + TOK)  [plain, used for last layer]
__global__ __launch_bounds__(256) void k_ln_fuse(const u16* __restrict__ YF,
                                                 u16* __restrict__ TOK,
                                                 const float* __restrict__ fb,
                                                 const float* __restrict__ w,
                                                 const float* __restrict__ b)
{
  int row  = blockIdx.x * 4 + (threadIdx.x >> 6);
  int lane = threadIdx.x & 63;
  int base = lane * 8;
  const u16* yf = YF + (size_t)row * 512 + base;
  u16* tp = TOK + (size_t)row * 512 + base;
  u16x8 yv = *(const u16x8*)yf;
  u16x8 tv = *(u16x8*)tp;
  float v[8]; float s = 0.f, qq = 0.f;
#pragma unroll
  for (int i = 0; i < 8; ++i) {
    v[i] = b2f(yv[i]) + fb[base + i] + b2f(tv[i]);
    s += v[i]; qq += v[i] * v[i];
  }
#pragma unroll
  for (int o = 32; o; o >>= 1) { s += __shfl_xor(s, o, 64); qq += __shfl_xor(qq, o, 64); }
  float mean = s * (1.f / 512.f);
  float rstd = rsqrtf(qq * (1.f / 512.f) - mean * mean + 1e-5f);
  u16x8 ov;
#pragma unroll
  for (int i = 0; i < 8; ++i)
    ov[i] = f2b((v[i] - mean) * rstd * w[base + i] + b[base + i]);
  *(u16x8*)tp = ov;
}

// TOK = LN_blk(LN_ss(YF + fus_b + TOK))  (fused; t stays in f32 regs)
__global__ __launch_bounds__(256)
void k_ln_fuse2(const u16* __restrict__ YF, u16* __restrict__ TOK,
                const float* __restrict__ fb, const float* __restrict__ w1,
                const float* __restrict__ b1, const float* __restrict__ w2,
                const float* __restrict__ b2)
{
  int row  = blockIdx.x * 4 + (threadIdx.x >> 6);
  int lane = threadIdx.x & 63;
  int base = lane * 8;
  const u16* yf = YF + (size_t)row * 512 + base;
  u16* tp = TOK + (size_t)row * 512 + base;
  u16x8 yv = *(const u16x8*)yf;
  u16x8 tv = *(u16x8*)tp;
  float v[8]; float s = 0.f, qq = 0.f;
#pragma unroll
  for (int i = 0; i < 8; ++i) {
    v[i] = b2f(yv[i]) + fb[base + i] + b2f(tv[i]);
    s += v[i]; qq += v[i] * v[i];
  }
#pragma unroll
  for (int o = 32; o; o >>= 1) { s += __shfl_xor(s, o, 64); qq += __shfl_xor(qq, o, 64); }
  float mean = s * (1.f / 512.f);
  float rstd = rsqrtf(qq * (1.f / 512.f) - mean * mean + 1e-5f);
  float s2 = 0.f, q2 = 0.f;
#pragma unroll
  for (int i = 0; i < 8; ++i) {
    v[i] = (v[i] - mean) * rstd * w1[base + i] + b1[base + i];
    s2 += v[i]; q2 += v[i] * v[i];
  }
#pragma unroll
  for (int o = 32; o; o >>= 1) { s2 += __shfl_xor(s2, o, 64); q2 += __shfl_xor(q2, o, 64); }
  float m2 = s2 * (1.f / 512.f);
  float r2 = rsqrtf(q2 * (1.f / 512.f) - m2 * m2 + 1e-5f);
  u16x8 ov;
#pragma unroll
  for (int i = 0; i < 8; ++i)
    ov[i] = f2b((v[i] - m2) * r2 * w2[base + i] + b2[base + i]);
  *(u16x8*)tp = ov;
}

// conv3+silu, h+v, 4 d's per thread (u16x4, 8B/lane)
__global__ __launch_bounds__(256)
void k_conv_hv(const u16* __restrict__ XZ,
               const float* __restrict__ cwh, const float* __restrict__ cbh,
               const float* __restrict__ cwv, const float* __restrict__ cbv,
               u16* __restrict__ XC)
{
  int idx = blockIdx.x * 256 + threadIdx.x;   // 2*896*192 = 344064
  int half = idx >= 172032;
  int t = idx - (half ? 172032 : 0);
  int dp = t % 192, sq = t / 192;
  int d0 = dp * 4;
  int rowbase, rowstride;
  if (!half) { rowbase = sq * 14; rowstride = 1; }
  else       { int b = sq / 14, wq = sq - b * 14; rowbase = b * 196 + wq; rowstride = 14; }
  const float* cw = half ? cwv : cwh;
  const float* cb = half ? cbv : cbh;
  int xio = half ? 1536 : 0, xco = half ? 768 : 0;
  float w0[4], w1[4], w2[4], bc[4];
#pragma unroll
  for (int i = 0; i < 4; ++i) {
    w0[i] = cw[(d0 + i) * 3 + 0];
    w1[i] = cw[(d0 + i) * 3 + 1];
    w2[i] = cw[(d0 + i) * 3 + 2];
    bc[i] = cb[d0 + i];
  }
  u16x4 cu = *(const u16x4*)&XZ[(size_t)rowbase * 3072 + xio + d0];
  float p[4] = {0.f, 0.f, 0.f, 0.f}, c[4], n[4];
#pragma unroll
  for (int i = 0; i < 4; ++i) c[i] = b2f(cu[i]);
#pragma unroll
  for (int l = 0; l < 14; ++l) {
    int row = rowbase + l * rowstride;
    if (l < 13) {
      u16x4 nu = *(const u16x4*)&XZ[(size_t)(row + rowstride) * 3072 + xio + d0];
#pragma unroll
      for (int i = 0; i < 4; ++i) n[i] = b2f(nu[i]);
    } else {
#pragma unroll
      for (int i = 0; i < 4; ++i) n[i] = 0.f;
    }
    u16x4 ov;
#pragma unroll
    for (int i = 0; i < 4; ++i)
      ov[i] = f2b(fsilu(p[i] * w0[i] + c[i] * w1[i] + n[i] * w2[i] + bc[i]));
    *(u16x4*)&XC[(size_t)row * 1536 + xco + d0] = ov;
#pragma unroll
    for (int i = 0; i < 4; ++i) { p[i] = c[i]; c[i] = n[i]; }
  }
}

// selective scan, h+v, 4 d's per thread (u16x4, 8B/lane)
__global__ __launch_bounds__(256)
void k_scan_hv(const u16* __restrict__ XZ, u16* __restrict__ XC,
               const float* __restrict__ dtbh, const float* __restrict__ Ah,
               const float* __restrict__ Dh,
               const float* __restrict__ dtbv, const float* __restrict__ Av,
               const float* __restrict__ Dv)
{
  int idx = blockIdx.x * 256 + threadIdx.x;   // 2*896*192 = 344064
  int half = idx >= 172032;
  int t = idx - (half ? 172032 : 0);
  int dp = t % 192, sq = t / 192;
  int d0 = dp * 4;
  int rowbase, rowstride;
  if (!half) { rowbase = sq * 14; rowstride = 1; }
  else       { int b = sq / 14, wq = sq - b * 14; rowbase = b * 196 + wq; rowstride = 14; }
  int xio = half ? 1536 : 0, xco = half ? 768 : 0;
  const float* dtb = half ? dtbv : dtbh;
  const float* Ap  = half ? Av : Ah;
  const float* Dp  = half ? Dv : Dh;
  float db[4], Aa[4], Da[4], r[4];
#pragma unroll
  for (int i = 0; i < 4; ++i) {
    db[i] = dtb[d0 + i]; Aa[i] = Ap[d0 + i]; Da[i] = Dp[d0 + i]; r[i] = 0.f;
  }
#pragma unroll
  for (int l = 0; l < 14; ++l) {
    int row = rowbase + l * rowstride;
    size_t zb  = (size_t)row * 3072 + xio;
    size_t cbo = (size_t)row * 1536 + xco;
    u16x4 xcu = *(const u16x4*)&XC[cbo + d0];
    u16x4 dtu = *(const u16x4*)&XZ[zb + d0];
    u16x4 zu  = *(const u16x4*)&XZ[zb + 768 + d0];
    u16x4 ov;
#pragma unroll
    for (int i = 0; i < 4; ++i) {
      float xc = b2f(xcu[i]);
      float dt = fsoftplus(b2f(dtu[i]) + db[i]);
      float ae = fexp(Aa[i] * dt);
      r[i] += xc * dt * ae;
      float z = b2f(zu[i]);
      float y = (r[i] * ae + xc * Da[i]) * (z * fsigmoid(z));
      ov[i] = f2b(y);
    }
    *(u16x4*)&XC[cbo + d0] = ov;
  }
}

// cls token path (batch-invariant, f32)
__global__ void k_cls(const float* __restrict__ cls_tok,
                      const float* __restrict__ pos,
                      const float* __restrict__ bw, const float* __restrict__ bb,
                      float* __restrict__ CLS)
{
  __shared__ float rs[8], rq[8], stat[2];
  int n = threadIdx.x;
  float v = cls_tok[n] + pos[n];
  for (int l = 0; l < 6; ++l) {
    float s = v, q = v * v;
#pragma unroll
    for (int o = 32; o; o >>= 1) { s += __shfl_xor(s, o, 64); q += __shfl_xor(q, o, 64); }
    if ((n & 63) == 0) { rs[n >> 6] = s; rq[n >> 6] = q; }
    __syncthreads();
    if (n == 0) {
      float S = 0.f, Q = 0.f;
      for (int i = 0; i < 8; ++i) { S += rs[i]; Q += rq[i]; }
      float m = S * (1.f / 512.f);
      stat[0] = m; stat[1] = rsqrtf(Q * (1.f / 512.f) - m * m + 1e-5f);
    }
    __syncthreads();
    float u = (v - stat[0]) * stat[1] * bw[l * 512 + n] + bb[l * 512 + n];
    v = v + u;
    __syncthreads();
  }
  CLS[n] = v;
}

// final LN -> f32 out
__global__ __launch_bounds__(256) void k_final(const u16* __restrict__ TOK,
                                               const float* __restrict__ CLS,
                                               const float* __restrict__ w,
                                               const float* __restrict__ b,
                                               float* __restrict__ out)
{
  int row  = blockIdx.x * 4 + (threadIdx.x >> 6);   // < 12608
  int lane = threadIdx.x & 63;
  int bi = row / 197;
  int t  = row - bi * 197;
  int base = lane * 8;
  float v[8]; float s = 0.f, qq = 0.f;
  if (t == 0) {
#pragma unroll
    for (int i = 0; i < 8; ++i) v[i] = CLS[base + i];
  } else {
    const u16* src = TOK + ((size_t)bi * 196 + (t - 1)) * 512 + base;
    u16x8 tv = *(const u16x8*)src;
#pragma unroll
    for (int i = 0; i < 8; ++i) v[i] = b2f(tv[i]);
  }
#pragma unroll
  for (int i = 0; i < 8; ++i) { s += v[i]; qq += v[i] * v[i]; }
#pragma unroll
  for (int o = 32; o; o >>= 1) { s += __shfl_xor(s, o, 64); qq += __shfl_xor(qq, o, 64); }
  float mean = s * (1.f / 512.f);
  float rstd = rsqrtf(qq * (1.f / 512.f) - mean * mean + 1e-5f);
  float* op = out + (size_t)row * 512 + base;
#pragma unroll
  for (int i = 0; i < 8; ++i)
    op[i] = (v[i] - mean) * rstd * w[base + i] + b[base + i];
}

// ---------------------------------------------------------------------------
extern "C" void kernel_launch(void* const* d_in, const int* in_sizes, int n_in,
                              void* d_out, int out_size, void* d_ws, size_t ws_size,
                              hipStream_t stream)
{
  const float* x        = (const float*)d_in[0];
  const float* patch_w  = (const float*)d_in[1];
  const float* patch_b  = (const float*)d_in[2];
  const float* cls_tok  = (const float*)d_in[3];
  const float* pos      = (const float*)d_in[4];
  const float* blk_w    = (const float*)d_in[5];
  const float* blk_b    = (const float*)d_in[6];
  const float* mh_in_w  = (const float*)d_in[7];
  const float* mh_out_w = (const float*)d_in[8];
  const float* mh_cw    = (const float*)d_in[9];
  const float* mh_cb    = (const float*)d_in[10];
  const float* mh_dtw   = (const float*)d_in[11];
  const float* mh_dtb   = (const float*)d_in[12];
  const float* mh_A     = (const float*)d_in[13];
  const float* mh_D     = (const float*)d_in[14];
  const float* mv_in_w  = (const float*)d_in[15];
  const float* mv_out_w = (const float*)d_in[16];
  const float* mv_cw    = (const float*)d_in[17];
  const float* mv_cb    = (const float*)d_in[18];
  const float* mv_dtw   = (const float*)d_in[19];
  const float* mv_dtb   = (const float*)d_in[20];
  const float* mv_A     = (const float*)d_in[21];
  const float* mv_D     = (const float*)d_in[22];
  const float* fus_w    = (const float*)d_in[23];
  const float* fus_b    = (const float*)d_in[24];
  const float* ss_w     = (const float*)d_in[25];
  const float* ss_b     = (const float*)d_in[26];
  const float* fn_w     = (const float*)d_in[27];
  const float* fn_b     = (const float*)d_in[28];

  // workspace layout (bytes), total ~198 MB (ws_size = 256 MiB):
  char* ws = (char*)d_ws;
  u16*   TOK  = (u16*)  (ws);                  // 12544x512  bf16  12,845,056
  u16*   XZHV = (u16*)  (ws +  12845056);      // 12544x3072 bf16  77,070,336
  u16*   XCHV = (u16*)  (ws +  89915392);      // 12544x1536 bf16  38,535,168
  u16*   WB   = (u16*)  (ws + 128450560);      // 6-layer bf16 wts 48,758,784
  u16*   WP   = (u16*)  (ws + 177209344);      // patch_w bf16        786,432
  u16*   OT   = (u16*)  (ws + 178782208);      // out^T bf16        9,437,184
  u16*   WF   = (u16*)  (ws + 188219392);      // W' fused          9,437,184
  float* CLS  = (float*)(ws + 197656576);      // 512 f32
  u16*   IM   = XCHV;                          // im2col aliases XCHV
  u16*   YF   = XZHV;                          // yf GEMM out aliases XZHV

  const size_t LS = 4063232;
  const size_t oMHI = 0, oMHD = 786432, oMVI = 1769472, oMVD = 2555904;

  // one-time: conversions, W' precompute, patch embed, cls
  k_cvt_all<<<9600, 256, 0, stream>>>(mh_in_w, mh_dtw,
                                      mv_in_w, mv_dtw, fus_w, WB);
  k_transp<<<dim3(24, 16, 12), 256, 0, stream>>>(mh_out_w, mv_out_w, OT);
  gemm_wprep<<<dim3(6, 4, 12), 256, 0, stream>>>(WB, OT, WF);
  k_cvt1<<<192, 256, 0, stream>>>(patch_w, WP);   // 393,216 elems exactly
  k_im2col<<<4704, 256, 0, stream>>>(x, IM);
  gemm_dual<<<dim3(4, 98), 256, 0, stream>>>(IM, WP, WP, TOK,
                                             768, 768, 512, 4, 0, 0);
  k_addbias_ln<<<3136, 256, 0, stream>>>(TOK, patch_b, pos, blk_w, blk_b);
  k_cls<<<1, 512, 0, stream>>>(cls_tok, pos, blk_w, blk_b, CLS);

  for (int L = 0; L < 6; ++L) {
    const u16* wl = WB + (size_t)L * LS;

    // in-proj (h cols 0..1535, v cols 1536..3071)
    gemm_dual<<<dim3(24, 98), 256, 0, stream>>>(
        TOK, wl + oMHI, wl + oMVI, XZHV, 512, 512, 3072, 12, 0, 1536);
    // conv3+silu
    k_conv_hv<<<1344, 256, 0, stream>>>(XZHV, mh_cw + L * 2304, mh_cb + L * 768,
                                        mv_cw + L * 2304, mv_cb + L * 768, XCHV);
    // dt-proj (dtraw overwrites xi slots of XZHV)
    gemm_dual<<<dim3(12, 98), 256, 0, stream>>>(
        XCHV, wl + oMHD, wl + oMVD, XZHV, 768, 1536, 3072, 6, 768, 1536);
    // selective scan (y overwrites xc in XCHV)
    k_scan_hv<<<1344, 256, 0, stream>>>(XZHV, XCHV,
                                        mh_dtb + L * 768, mh_A + L * 768, mh_D + L * 768,
                                        mv_dtb + L * 768, mv_A + L * 768, mv_D + L * 768);
    // fused out-proj + fusion: yf = XCHV @ W'^T  (K=1536, N=512)
    gemm_dual<<<dim3(4, 98), 256, 0, stream>>>(
        XCHV, WF + (size_t)L * 786432, WF + (size_t)L * 786432, YF,
        1536, 1536, 512, 4, 0, 0);
    // residual LN (+ next layer's LN fused, except last layer)
    if (L < 5) {
      k_ln_fuse2<<<3136, 256, 0, stream>>>(YF, TOK, fus_b + L * 512,
                                           ss_w + L * 512, ss_b + L * 512,
                                           blk_w + (L + 1) * 512, blk_b + (L + 1) * 512);
    } else {
      k_ln_fuse<<<3136, 256, 0, stream>>>(YF, TOK, fus_b + L * 512,
                                          ss_w + L * 512, ss_b + L * 512);
    }
  }

  k_final<<<3152, 256, 0, stream>>>(TOK, CLS, fn_w, fn_b, (float*)d_out);
  (void)in_sizes; (void)n_in; (void)out_size; (void)ws_size;
}